// Round 1
// baseline (9047.738 us; speedup 1.0000x reference)
//
#include <hip/hip_runtime.h>
#include <cstdint>
#include <math.h>

// ---------------------------------------------------------------------------
// Quantization-aware BERT-base forward (B=8,S=512,H=768,L=12,FF=3072).
// Strategy: the fake-quant linears are computed EXACTLY via int8 MFMA:
//   y = sx*sw*( mfma_i8(xq-128, wq) + (128-zp)*rowsum(wq) ) + bias
// Weights are re-quantized into ws each call (harness forbids static state).
// Attention / LN / gelu in fp32.
// ---------------------------------------------------------------------------

#define NLAYER 12
#define HID 768
#define NHEAD 12
#define DHEAD 64
#define FFDIM 3072
#define NTOK 4096
#define SEQ 512

typedef __attribute__((ext_vector_type(4))) int   i32x4;
typedef __attribute__((ext_vector_type(4))) float f32x4;

// ---------------- ws layout (bytes) ----------------
#define WQ8_Q ((size_t)0)
#define WQ8_K ((size_t)7077888)
#define WQ8_V ((size_t)14155776)
#define WQ8_O ((size_t)21233664)
#define WQ8_I ((size_t)28311552)
#define WQ8_D ((size_t)56623104)
#define OFF_WSUM  ((size_t)84934656)
#define WS_Q 0
#define WS_K 9216
#define WS_V 18432
#define WS_O 27648
#define WS_I 36864
#define WS_D 73728
#define OFF_WABS  (OFF_WSUM + 331776)     // 72 uint slots (abs-max bits)
#define OFF_ACTMM (OFF_WABS + 512)        // {scale, zp}
#define OFF_PART  (OFF_ACTMM + 256)       // 1024 float2 partials
#define OFF_X     (OFF_PART + 16384)      // residual, 4096x768 f32
#define OFF_T     (OFF_X + 12582912)      // q,k,v,ctx (4x12.6MB) OR h (4096x3072)
#define OFF_Y     (OFF_T + 50331648)      // gemm out 4096x768 f32
#define OFF_A8    (OFF_Y + 12582912)      // quantized activation int8 (<=4096x3072)
#define WS_NEED   (OFF_A8 + 12582912)

// ---------------- helpers ----------------
__device__ __forceinline__ float blockReduceSumB(float v) {
  __shared__ float sm[4];
  int lane = threadIdx.x & 63, wv = threadIdx.x >> 6;
#pragma unroll
  for (int o = 32; o > 0; o >>= 1) v += __shfl_down(v, o, 64);
  if (lane == 0) sm[wv] = v;
  __syncthreads();
  float r = sm[0] + sm[1] + sm[2] + sm[3];
  __syncthreads();
  return r;
}

// ---------------- weight prep ----------------
__global__ void k_winit(unsigned* wabs) {
  if (threadIdx.x < 72) wabs[threadIdx.x] = 0u;
}

__global__ __launch_bounds__(256) void k_wabsmax(const float* __restrict__ w,
    unsigned* __restrict__ slots, int ept, int cpt) {
  int t = blockIdx.x / cpt, c = blockIdx.x % cpt;
  const float* wt = w + (size_t)t * ept + (size_t)c * 32768;
  float m = 0.f;
  for (int i = threadIdx.x * 4; i < 32768; i += 1024) {
    f32x4 v = *(const f32x4*)(wt + i);
    m = fmaxf(m, fmaxf(fmaxf(fabsf(v.x), fabsf(v.y)), fmaxf(fabsf(v.z), fabsf(v.w))));
  }
  __shared__ float sm[4];
  int lane = threadIdx.x & 63, wv = threadIdx.x >> 6;
#pragma unroll
  for (int o = 32; o > 0; o >>= 1) m = fmaxf(m, __shfl_xor(m, o, 64));
  if (lane == 0) sm[wv] = m;
  __syncthreads();
  if (threadIdx.x == 0) {
    m = fmaxf(fmaxf(sm[0], sm[1]), fmaxf(sm[2], sm[3]));
    atomicMax(slots + t, __float_as_uint(m));
  }
}

// one wave per output row: quantize to int8 + row sum
__global__ __launch_bounds__(256) void k_wquant(const float* __restrict__ w,
    int8_t* __restrict__ wq, int* __restrict__ wsum, const unsigned* __restrict__ slots,
    int O, int K) {
  int row = blockIdx.x * 4 + (threadIdx.x >> 6);
  int lane = threadIdx.x & 63;
  int t = row / O;
  float sw = fmaxf(__uint_as_float(slots[t]) / 127.0f, 1e-8f);
  float inv = 1.0f / sw;
  const float* wr = w + (size_t)row * K;
  int8_t* wqr = wq + (size_t)row * K;
  int epl = K >> 6;
  int base = lane * epl;
  int ssum = 0;
  for (int i = 0; i < epl; i += 4) {
    f32x4 v = *(const f32x4*)(wr + base + i);
    int q0 = (int)fminf(fmaxf(rintf(v.x * inv), -127.f), 127.f);
    int q1 = (int)fminf(fmaxf(rintf(v.y * inv), -127.f), 127.f);
    int q2 = (int)fminf(fmaxf(rintf(v.z * inv), -127.f), 127.f);
    int q3 = (int)fminf(fmaxf(rintf(v.w * inv), -127.f), 127.f);
    ssum += q0 + q1 + q2 + q3;
    *(int*)(wqr + base + i) = (q0 & 0xff) | ((q1 & 0xff) << 8) | ((q2 & 0xff) << 16) | ((q3 & 0xff) << 24);
  }
#pragma unroll
  for (int o = 32; o > 0; o >>= 1) ssum += __shfl_down(ssum, o, 64);
  if (lane == 0) wsum[row] = ssum;
}

// ---------------- embeddings + LN ----------------
__global__ __launch_bounds__(256) void k_embed(const int* __restrict__ ids,
    const float* __restrict__ we, const float* __restrict__ pe, const float* __restrict__ te,
    const float* __restrict__ g, const float* __restrict__ bb, float* __restrict__ x) {
  int tok = blockIdx.x;
  int s = tok & (SEQ - 1);
  int id = ids[tok];
  const float* wrow = we + (size_t)id * HID;
  const float* prow = pe + (size_t)s * HID;
  int c0 = threadIdx.x * 3;
  float e0 = wrow[c0]     + prow[c0]     + te[c0];
  float e1 = wrow[c0 + 1] + prow[c0 + 1] + te[c0 + 1];
  float e2 = wrow[c0 + 2] + prow[c0 + 2] + te[c0 + 2];
  float mean = blockReduceSumB(e0 + e1 + e2) * (1.0f / 768.0f);
  float d0 = e0 - mean, d1 = e1 - mean, d2 = e2 - mean;
  float var = blockReduceSumB(d0 * d0 + d1 * d1 + d2 * d2) * (1.0f / 768.0f);
  float rs = 1.0f / sqrtf(var + 1e-12f);
  float* xr = x + (size_t)tok * HID;
  xr[c0]     = d0 * rs * g[c0]     + bb[c0];
  xr[c0 + 1] = d1 * rs * g[c0 + 1] + bb[c0 + 1];
  xr[c0 + 2] = d2 * rs * g[c0 + 2] + bb[c0 + 2];
}

// ---------------- residual + LN ----------------
__global__ __launch_bounds__(256) void k_lnres(const float* __restrict__ res,
    const float* __restrict__ y, const float* __restrict__ g, const float* __restrict__ bb,
    float* __restrict__ out) {
  int tok = blockIdx.x;
  int c0 = threadIdx.x * 3;
  const float* rr = res + (size_t)tok * HID;
  const float* yr = y + (size_t)tok * HID;
  float e0 = rr[c0]     + yr[c0];
  float e1 = rr[c0 + 1] + yr[c0 + 1];
  float e2 = rr[c0 + 2] + yr[c0 + 2];
  float mean = blockReduceSumB(e0 + e1 + e2) * (1.0f / 768.0f);
  float d0 = e0 - mean, d1 = e1 - mean, d2 = e2 - mean;
  float var = blockReduceSumB(d0 * d0 + d1 * d1 + d2 * d2) * (1.0f / 768.0f);
  float rs = 1.0f / sqrtf(var + 1e-12f);
  float* orow = out + (size_t)tok * HID;
  orow[c0]     = d0 * rs * g[c0]     + bb[c0];
  orow[c0 + 1] = d1 * rs * g[c0 + 1] + bb[c0 + 1];
  orow[c0 + 2] = d2 * rs * g[c0 + 2] + bb[c0 + 2];
}

// ---------------- activation min/max (pass 1) ----------------
__global__ __launch_bounds__(256) void k_minmax(const float* __restrict__ x, int n,
    float2* __restrict__ part) {
  float mn = 0.f, mx = 0.f;  // seed 0 matches reference min(.,0)/max(.,0)
  int stride = gridDim.x * 1024;
  for (int i = (blockIdx.x * 256 + threadIdx.x) * 4; i < n; i += stride) {
    f32x4 v = *(const f32x4*)(x + i);
    mn = fminf(mn, fminf(fminf(v.x, v.y), fminf(v.z, v.w)));
    mx = fmaxf(mx, fmaxf(fmaxf(v.x, v.y), fmaxf(v.z, v.w)));
  }
  __shared__ float smn[4], smx[4];
  int lane = threadIdx.x & 63, wv = threadIdx.x >> 6;
#pragma unroll
  for (int o = 32; o > 0; o >>= 1) {
    mn = fminf(mn, __shfl_xor(mn, o, 64));
    mx = fmaxf(mx, __shfl_xor(mx, o, 64));
  }
  if (lane == 0) { smn[wv] = mn; smx[wv] = mx; }
  __syncthreads();
  if (threadIdx.x == 0) {
    mn = fminf(fminf(smn[0], smn[1]), fminf(smn[2], smn[3]));
    mx = fmaxf(fmaxf(smx[0], smx[1]), fmaxf(smx[2], smx[3]));
    part[blockIdx.x] = make_float2(mn, mx);
  }
}

// ---------------- finalize minmax + quantize activation ----------------
__global__ __launch_bounds__(256) void k_actquant(const float* __restrict__ x, int n,
    const float2* __restrict__ part, float* __restrict__ slot, int8_t* __restrict__ xq) {
  float mn = 0.f, mx = 0.f;
  for (int i = threadIdx.x; i < 1024; i += 256) {
    float2 p = part[i];
    mn = fminf(mn, p.x);
    mx = fmaxf(mx, p.y);
  }
  __shared__ float smn[4], smx[4];
  int lane = threadIdx.x & 63, wv = threadIdx.x >> 6;
#pragma unroll
  for (int o = 32; o > 0; o >>= 1) {
    mn = fminf(mn, __shfl_xor(mn, o, 64));
    mx = fmaxf(mx, __shfl_xor(mx, o, 64));
  }
  if (lane == 0) { smn[wv] = mn; smx[wv] = mx; }
  __syncthreads();
  mn = fminf(fminf(smn[0], smn[1]), fminf(smn[2], smn[3]));
  mx = fmaxf(fmaxf(smx[0], smx[1]), fmaxf(smx[2], smx[3]));
  float scale = fmaxf((mx - mn) / 255.0f, 1e-8f);
  float zp = fminf(fmaxf(rintf(-mn / scale), 0.0f), 255.0f);
  if (blockIdx.x == 0 && threadIdx.x == 0) { slot[0] = scale; slot[1] = zp; }
  float inv = 1.0f / scale;
  int stride = gridDim.x * 1024;
  for (int i = (blockIdx.x * 256 + threadIdx.x) * 4; i < n; i += stride) {
    f32x4 v = *(const f32x4*)(x + i);
    int q0 = (int)(fminf(fmaxf(rintf(v.x * inv) + zp, 0.f), 255.f)) - 128;
    int q1 = (int)(fminf(fmaxf(rintf(v.y * inv) + zp, 0.f), 255.f)) - 128;
    int q2 = (int)(fminf(fmaxf(rintf(v.z * inv) + zp, 0.f), 255.f)) - 128;
    int q3 = (int)(fminf(fmaxf(rintf(v.w * inv) + zp, 0.f), 255.f)) - 128;
    *(int*)(xq + i) = (q0 & 0xff) | ((q1 & 0xff) << 8) | ((q2 & 0xff) << 16) | ((q3 & 0xff) << 24);
  }
}

// ---------------- int8 GEMM: out[M,N] = sx*sw*(A8 @ W8^T + dz*wsum) + bias ----
// A: M x K int8 (xq-128), W: N x K int8. 64x64 block tile, 4 waves of 32x32.
__global__ __launch_bounds__(256) void k_gemm_i8(
    const int8_t* __restrict__ A, const int8_t* __restrict__ W,
    const int* __restrict__ wsum, const unsigned* __restrict__ wabs,
    const float* __restrict__ actmm, const float* __restrict__ bias,
    float* __restrict__ out, int N, int K, int gelu) {
  int nb = N >> 6;
  int m0 = (blockIdx.x / nb) << 6;
  int n0 = (blockIdx.x % nb) << 6;
  int wid = threadIdx.x >> 6, lane = threadIdx.x & 63;
  int mw = m0 + ((wid >> 1) << 5);
  int nw = n0 + ((wid & 1) << 5);
  int r = lane & 15, kq = lane >> 4;
  const int8_t* Ap = A + (size_t)(mw + r) * K + (kq << 4);
  const int8_t* Wp = W + (size_t)(nw + r) * K + (kq << 4);
  i32x4 acc00 = {0, 0, 0, 0}, acc01 = {0, 0, 0, 0};
  i32x4 acc10 = {0, 0, 0, 0}, acc11 = {0, 0, 0, 0};
  for (int k0 = 0; k0 < K; k0 += 64) {
    i32x4 a0 = *(const i32x4*)(Ap + k0);
    i32x4 a1 = *(const i32x4*)(Ap + (size_t)16 * K + k0);
    i32x4 b0 = *(const i32x4*)(Wp + k0);
    i32x4 b1 = *(const i32x4*)(Wp + (size_t)16 * K + k0);
    acc00 = __builtin_amdgcn_mfma_i32_16x16x64_i8(a0, b0, acc00, 0, 0, 0);
    acc01 = __builtin_amdgcn_mfma_i32_16x16x64_i8(a0, b1, acc01, 0, 0, 0);
    acc10 = __builtin_amdgcn_mfma_i32_16x16x64_i8(a1, b0, acc10, 0, 0, 0);
    acc11 = __builtin_amdgcn_mfma_i32_16x16x64_i8(a1, b1, acc11, 0, 0, 0);
  }
  float sw = fmaxf(__uint_as_float(*wabs) / 127.0f, 1e-8f);
  float sx = actmm[0];
  int dz = 128 - (int)actmm[1];
  float s = sx * sw;
  int cc = lane & 15, cr = (lane >> 4) << 2;
  i32x4 accs[2][2] = {{acc00, acc01}, {acc10, acc11}};
#pragma unroll
  for (int fm = 0; fm < 2; fm++)
#pragma unroll
    for (int fn = 0; fn < 2; fn++) {
      int col = nw + fn * 16 + cc;
      float bv = bias[col];
      int wsv = wsum[col] * dz;
#pragma unroll
      for (int rg = 0; rg < 4; rg++) {
        int row = mw + fm * 16 + cr + rg;
        float y = s * (float)(accs[fm][fn][rg] + wsv) + bv;
        if (gelu) y = 0.5f * y * (1.0f + erff(y * 0.70710678f));
        out[(size_t)row * N + col] = y;
      }
    }
}

// ---------------- attention (fp32, per (b,h,qtile64)) ----------------
__global__ __launch_bounds__(256, 1) void k_attn(const float* __restrict__ q,
    const float* __restrict__ k, const float* __restrict__ v, float* __restrict__ ctx) {
  __shared__ float sc[64][516];
  int bid = blockIdx.x;
  int qt = bid & 7;
  int h = (bid >> 3) % NHEAD;
  int b = bid / (8 * NHEAD);
  int lane = threadIdx.x & 63, wv = threadIdx.x >> 6;
  // each lane owns q-row qi=lane in registers
  int qi = lane;
  const float* qrow = q + ((size_t)(b * SEQ + qt * 64 + qi)) * HID + h * DHEAD;
  f32x4 qr[16];
#pragma unroll
  for (int i = 0; i < 16; i++) qr[i] = *(const f32x4*)(qrow + i * 4);
  // scores: wave wv handles kj = wv + 4*it ; k row broadcast across lanes
  for (int kj = wv; kj < SEQ; kj += 4) {
    const float* krow = k + ((size_t)(b * SEQ + kj)) * HID + h * DHEAD;
    float s = 0.f;
#pragma unroll
    for (int i = 0; i < 16; i++) {
      f32x4 kv = *(const f32x4*)(krow + i * 4);
      s += qr[i].x * kv.x + qr[i].y * kv.y + qr[i].z * kv.z + qr[i].w * kv.w;
    }
    sc[qi][kj] = s * 0.125f;
  }
  __syncthreads();
  // softmax: each wave 16 rows
  for (int r0 = wv * 16; r0 < wv * 16 + 16; r0++) {
    float vals[8];
    float m = -1e30f;
#pragma unroll
    for (int j = 0; j < 8; j++) {
      vals[j] = sc[r0][lane + j * 64];
      m = fmaxf(m, vals[j]);
    }
#pragma unroll
    for (int o = 32; o > 0; o >>= 1) m = fmaxf(m, __shfl_xor(m, o, 64));
    float sum = 0.f;
#pragma unroll
    for (int j = 0; j < 8; j++) { vals[j] = expf(vals[j] - m); sum += vals[j]; }
#pragma unroll
    for (int o = 32; o > 0; o >>= 1) sum += __shfl_xor(sum, o, 64);
    float rinv = 1.0f / sum;
#pragma unroll
    for (int j = 0; j < 8; j++) sc[r0][lane + j * 64] = vals[j] * rinv;
  }
  __syncthreads();
  // PV: lane owns d=lane; wave wv owns q rows wv*16..wv*16+15; v row reused across 16 rows
  float acc[16];
#pragma unroll
  for (int i = 0; i < 16; i++) acc[i] = 0.f;
  int d = lane;
  for (int kj = 0; kj < SEQ; kj += 4) {
    const float* vrow = v + ((size_t)(b * SEQ + kj)) * HID + h * DHEAD + d;
    float v0 = vrow[0], v1 = vrow[HID], v2 = vrow[2 * HID], v3 = vrow[3 * HID];
#pragma unroll
    for (int i = 0; i < 16; i++) {
      f32x4 p = *(const f32x4*)&sc[wv * 16 + i][kj];
      acc[i] += p.x * v0 + p.y * v1 + p.z * v2 + p.w * v3;
    }
  }
#pragma unroll
  for (int i = 0; i < 16; i++) {
    int qi2 = wv * 16 + i;
    ctx[((size_t)(b * SEQ + qt * 64 + qi2)) * HID + h * DHEAD + d] = acc[i];
  }
}

// ---------------------------------------------------------------------------
extern "C" void kernel_launch(void* const* d_in, const int* in_sizes, int n_in,
                              void* d_out, int out_size, void* d_ws, size_t ws_size,
                              hipStream_t stream) {
  if (ws_size < WS_NEED) return;  // workspace too small: bail (output stays wrong but no corruption)

  const int*   ids = (const int*)d_in[0];
  const float* we  = (const float*)d_in[1];
  const float* pe  = (const float*)d_in[2];
  const float* te  = (const float*)d_in[3];
  const float* elg = (const float*)d_in[4];
  const float* elb = (const float*)d_in[5];
  const float* Wq  = (const float*)d_in[6];
  const float* bq  = (const float*)d_in[7];
  const float* Wk  = (const float*)d_in[8];
  const float* bk  = (const float*)d_in[9];
  const float* Wv  = (const float*)d_in[10];
  const float* bv  = (const float*)d_in[11];
  const float* Wo  = (const float*)d_in[12];
  const float* bo  = (const float*)d_in[13];
  const float* l1g = (const float*)d_in[14];
  const float* l1b = (const float*)d_in[15];
  const float* Wi  = (const float*)d_in[16];
  const float* bi  = (const float*)d_in[17];
  const float* Wd  = (const float*)d_in[18];
  const float* bd  = (const float*)d_in[19];
  const float* l2g = (const float*)d_in[20];
  const float* l2b = (const float*)d_in[21];

  char* ws = (char*)d_ws;
  int8_t*   wq8   = (int8_t*)(ws);
  int*      wsum  = (int*)(ws + OFF_WSUM);
  unsigned* wabs  = (unsigned*)(ws + OFF_WABS);
  float*    actmm = (float*)(ws + OFF_ACTMM);
  float2*   part  = (float2*)(ws + OFF_PART);
  float*    X  = (float*)(ws + OFF_X);
  float*    T  = (float*)(ws + OFF_T);
  float*    Y  = (float*)(ws + OFF_Y);
  int8_t*   A8 = (int8_t*)(ws + OFF_A8);
  float* T0 = T;
  float* T1 = T + 3145728;
  float* T2 = T + 2 * 3145728;
  float* T3 = T + 3 * 3145728;

  // ---- per-call weight quantization ----
  k_winit<<<1, 128, 0, stream>>>(wabs);
  k_wabsmax<<<216, 256, 0, stream>>>(Wq, wabs + 0,  589824, 18);
  k_wabsmax<<<216, 256, 0, stream>>>(Wk, wabs + 12, 589824, 18);
  k_wabsmax<<<216, 256, 0, stream>>>(Wv, wabs + 24, 589824, 18);
  k_wabsmax<<<216, 256, 0, stream>>>(Wo, wabs + 36, 589824, 18);
  k_wabsmax<<<864, 256, 0, stream>>>(Wi, wabs + 48, 2359296, 72);
  k_wabsmax<<<864, 256, 0, stream>>>(Wd, wabs + 60, 2359296, 72);
  k_wquant<<<2304, 256, 0, stream>>>(Wq, wq8 + WQ8_Q, wsum + WS_Q, wabs + 0,  768, 768);
  k_wquant<<<2304, 256, 0, stream>>>(Wk, wq8 + WQ8_K, wsum + WS_K, wabs + 12, 768, 768);
  k_wquant<<<2304, 256, 0, stream>>>(Wv, wq8 + WQ8_V, wsum + WS_V, wabs + 24, 768, 768);
  k_wquant<<<2304, 256, 0, stream>>>(Wo, wq8 + WQ8_O, wsum + WS_O, wabs + 36, 768, 768);
  k_wquant<<<9216, 256, 0, stream>>>(Wi, wq8 + WQ8_I, wsum + WS_I, wabs + 48, 3072, 768);
  k_wquant<<<2304, 256, 0, stream>>>(Wd, wq8 + WQ8_D, wsum + WS_D, wabs + 60, 768, 3072);

  // ---- embeddings ----
  k_embed<<<4096, 256, 0, stream>>>(ids, we, pe, te, elg, elb, X);

  // ---- layers ----
  for (int l = 0; l < NLAYER; l++) {
    // QKV (share activation quantization of X)
    k_minmax<<<1024, 256, 0, stream>>>(X, NTOK * HID, part);
    k_actquant<<<1024, 256, 0, stream>>>(X, NTOK * HID, part, actmm, A8);
    k_gemm_i8<<<64 * 12, 256, 0, stream>>>(A8, wq8 + WQ8_Q + (size_t)l * 589824,
        wsum + WS_Q + l * 768, wabs + 0 + l, actmm, bq + l * 768, T0, 768, 768, 0);
    k_gemm_i8<<<64 * 12, 256, 0, stream>>>(A8, wq8 + WQ8_K + (size_t)l * 589824,
        wsum + WS_K + l * 768, wabs + 12 + l, actmm, bk + l * 768, T1, 768, 768, 0);
    k_gemm_i8<<<64 * 12, 256, 0, stream>>>(A8, wq8 + WQ8_V + (size_t)l * 589824,
        wsum + WS_V + l * 768, wabs + 24 + l, actmm, bv + l * 768, T2, 768, 768, 0);
    k_attn<<<768, 256, 0, stream>>>(T0, T1, T2, T3);
    // O-proj + LN1
    k_minmax<<<1024, 256, 0, stream>>>(T3, NTOK * HID, part);
    k_actquant<<<1024, 256, 0, stream>>>(T3, NTOK * HID, part, actmm, A8);
    k_gemm_i8<<<64 * 12, 256, 0, stream>>>(A8, wq8 + WQ8_O + (size_t)l * 589824,
        wsum + WS_O + l * 768, wabs + 36 + l, actmm, bo + l * 768, Y, 768, 768, 0);
    k_lnres<<<4096, 256, 0, stream>>>(X, Y, l1g + l * 768, l1b + l * 768, X);
    // FFN up (+gelu fused)
    k_minmax<<<1024, 256, 0, stream>>>(X, NTOK * HID, part);
    k_actquant<<<1024, 256, 0, stream>>>(X, NTOK * HID, part, actmm, A8);
    k_gemm_i8<<<64 * 48, 256, 0, stream>>>(A8, wq8 + WQ8_I + (size_t)l * 2359296,
        wsum + WS_I + l * 3072, wabs + 48 + l, actmm, bi + l * 3072, T, 3072, 768, 1);
    // FFN down + LN2
    k_minmax<<<1024, 256, 0, stream>>>(T, NTOK * FFDIM, part);
    k_actquant<<<1024, 256, 0, stream>>>(T, NTOK * FFDIM, part, actmm, A8);
    k_gemm_i8<<<64 * 12, 256, 0, stream>>>(A8, wq8 + WQ8_D + (size_t)l * 2359296,
        wsum + WS_D + l * 768, wabs + 60 + l, actmm, bd + l * 768, Y, 768, 3072, 0);
    k_lnres<<<4096, 256, 0, stream>>>(X, Y, l2g + l * 768, l2b + l * 768, X);
  }

  hipMemcpyAsync(d_out, X, (size_t)NTOK * HID * sizeof(float),
                 hipMemcpyDeviceToDevice, stream);
}